// Round 1
// baseline (6299.368 us; speedup 1.0000x reference)
//
#include <hip/hip_runtime.h>

#define N_NODES 50000
#define N_EDGES 800000
#define D 256
#define NCLS 40
#define BN_EPS 1e-5f

// ---------------- degree ----------------
__global__ void k_deg(const int* __restrict__ dst, float* __restrict__ deg) {
  int i = blockIdx.x * blockDim.x + threadIdx.x;
  int stride = gridDim.x * blockDim.x;
  for (; i < N_EDGES; i += stride) atomicAdd(&deg[dst[i]], 1.0f);
}

__global__ void k_invdeg(float* deg) {
  int i = blockIdx.x * blockDim.x + threadIdx.x;
  if (i < N_NODES) deg[i] = 1.0f / fmaxf(deg[i], 1.0f);
}

// ---------------- edge scatter (sum of feat[src] into agg[dst]) ----------------
// one wave per edge; lane handles 4 contiguous channels (float4 gather, 4 atomics)
__global__ void k_scatter256(const float* __restrict__ feat, const int* __restrict__ src,
                             const int* __restrict__ dst, float* __restrict__ agg) {
  int lane = threadIdx.x & 63;
  int wave = blockIdx.x * (blockDim.x >> 6) + (threadIdx.x >> 6);
  int nwaves = gridDim.x * (blockDim.x >> 6);
  for (int e = wave; e < N_EDGES; e += nwaves) {
    int s = src[e], d = dst[e];
    float4 v = *(const float4*)&feat[(size_t)s * D + lane * 4];
    float* out = &agg[(size_t)d * D + lane * 4];
    atomicAdd(out + 0, v.x);
    atomicAdd(out + 1, v.y);
    atomicAdd(out + 2, v.z);
    atomicAdd(out + 3, v.w);
  }
}

// 40-dim variant reading cols [40,80) of a row-stride-80 matrix (the neigh projection)
__global__ void k_scatter40(const float* __restrict__ P, const int* __restrict__ src,
                            const int* __restrict__ dst, float* __restrict__ agg40) {
  int lane = threadIdx.x & 63;
  int wave = blockIdx.x * (blockDim.x >> 6) + (threadIdx.x >> 6);
  int nwaves = gridDim.x * (blockDim.x >> 6);
  for (int e = wave; e < N_EDGES; e += nwaves) {
    if (lane < NCLS) {
      int s = src[e], d = dst[e];
      atomicAdd(&agg40[(size_t)d * NCLS + lane], P[(size_t)s * 80 + NCLS + lane]);
    }
  }
}

// ---------------- fused dual GEMM: Out = A1@W1^T + (A2*invdeg)@W2^T (+bias) ----------------
// fp32 vector GEMM. 128x128 tile, BK=16, 256 threads, 8x8 outputs/thread.
template <bool DUAL, bool HASBIAS>
__global__ __launch_bounds__(256) void k_gemm(
    const float* __restrict__ A1, const float* __restrict__ A2,
    const float* __restrict__ invdeg,
    const float* __restrict__ W1, const float* __restrict__ W2,
    const float* __restrict__ bias,
    float* __restrict__ Out, int M, int ncolB, int ldc) {
  __shared__ float As1[16][132], Bs1[16][132], As2[16][132], Bs2[16][132];
  int tid = threadIdx.x;
  int m0 = blockIdx.x * 128, n0 = blockIdx.y * 128;
  int tx = tid & 15, ty = tid >> 4;
  float acc[8][8] = {};
  for (int k0 = 0; k0 < D; k0 += 16) {
#pragma unroll
    for (int p = 0; p < 2; ++p) {
      int idx = tid + p * 256;   // 0..511
      int r = idx >> 2;          // 0..127
      int kq = (idx & 3) << 2;   // 0,4,8,12
      int row = m0 + r; if (row > M - 1) row = M - 1;
      float4 a1 = *(const float4*)&A1[(size_t)row * D + k0 + kq];
      As1[kq + 0][r] = a1.x; As1[kq + 1][r] = a1.y;
      As1[kq + 2][r] = a1.z; As1[kq + 3][r] = a1.w;
      if (DUAL) {
        float id = invdeg[row];
        float4 a2 = *(const float4*)&A2[(size_t)row * D + k0 + kq];
        As2[kq + 0][r] = a2.x * id; As2[kq + 1][r] = a2.y * id;
        As2[kq + 2][r] = a2.z * id; As2[kq + 3][r] = a2.w * id;
      }
      int rb = n0 + r; if (rb > ncolB - 1) rb = ncolB - 1;
      float4 b1 = *(const float4*)&W1[(size_t)rb * D + k0 + kq];
      Bs1[kq + 0][r] = b1.x; Bs1[kq + 1][r] = b1.y;
      Bs1[kq + 2][r] = b1.z; Bs1[kq + 3][r] = b1.w;
      if (DUAL) {
        float4 b2 = *(const float4*)&W2[(size_t)rb * D + k0 + kq];
        Bs2[kq + 0][r] = b2.x; Bs2[kq + 1][r] = b2.y;
        Bs2[kq + 2][r] = b2.z; Bs2[kq + 3][r] = b2.w;
      }
    }
    __syncthreads();
#pragma unroll
    for (int kk = 0; kk < 16; ++kk) {
      float a1v[8], b1v[8];
      *(float4*)&a1v[0] = *(const float4*)&As1[kk][ty * 8];
      *(float4*)&a1v[4] = *(const float4*)&As1[kk][ty * 8 + 4];
      *(float4*)&b1v[0] = *(const float4*)&Bs1[kk][tx * 8];
      *(float4*)&b1v[4] = *(const float4*)&Bs1[kk][tx * 8 + 4];
#pragma unroll
      for (int i = 0; i < 8; ++i)
#pragma unroll
        for (int j = 0; j < 8; ++j) acc[i][j] += a1v[i] * b1v[j];
      if (DUAL) {
        float a2v[8], b2v[8];
        *(float4*)&a2v[0] = *(const float4*)&As2[kk][ty * 8];
        *(float4*)&a2v[4] = *(const float4*)&As2[kk][ty * 8 + 4];
        *(float4*)&b2v[0] = *(const float4*)&Bs2[kk][tx * 8];
        *(float4*)&b2v[4] = *(const float4*)&Bs2[kk][tx * 8 + 4];
#pragma unroll
        for (int i = 0; i < 8; ++i)
#pragma unroll
          for (int j = 0; j < 8; ++j) acc[i][j] += a2v[i] * b2v[j];
      }
    }
    __syncthreads();
  }
#pragma unroll
  for (int i = 0; i < 8; ++i) {
    int row = m0 + ty * 8 + i;
    if (row >= M) break;
#pragma unroll
    for (int j = 0; j < 8; j += 4) {
      int col = n0 + tx * 8 + j;
      if (col + 3 < ncolB) {
        float4 o;
        o.x = acc[i][j + 0]; o.y = acc[i][j + 1];
        o.z = acc[i][j + 2]; o.w = acc[i][j + 3];
        if (HASBIAS) {
          o.x += bias[col + 0]; o.y += bias[col + 1];
          o.z += bias[col + 2]; o.w += bias[col + 3];
        }
        *(float4*)&Out[(size_t)row * ldc + col] = o;
      } else {
        for (int q = 0; q < 4; ++q) {
          if (col + q < ncolB) {
            float v = acc[i][j + q];
            if (HASBIAS) v += bias[col + q];
            Out[(size_t)row * ldc + col + q] = v;
          }
        }
      }
    }
  }
}

// ---------------- batch-norm stats: per-channel sum / sumsq ----------------
__global__ void k_stats(const float* __restrict__ x, float* __restrict__ stats) {
  int c = threadIdx.x;  // 256
  float s = 0.f, ss = 0.f;
  for (int r = blockIdx.x; r < N_NODES; r += gridDim.x) {
    float v = x[(size_t)r * D + c];
    s += v; ss += v * v;
  }
  atomicAdd(&stats[c], s);
  atomicAdd(&stats[D + c], ss);
}

// per-channel scale/shift: scale = rsqrt(var+eps)*w ; shift = b - mean*scale
__global__ void k_bnparams(const float* __restrict__ stats, const float* __restrict__ w,
                           const float* __restrict__ b, float* __restrict__ bnp) {
  int set = blockIdx.x, c = threadIdx.x;
  const float* st = stats + (size_t)set * 2 * D;
  float m = st[c] * (1.0f / N_NODES);
  float var = st[D + c] * (1.0f / N_NODES) - m * m;
  float sc = rsqrtf(var + BN_EPS) * w[c];
  bnp[(size_t)set * 2 * D + c] = sc;
  bnp[(size_t)set * 2 * D + D + c] = b[c] - m * sc;
}

// out = relu(h*sc0 + sh0 [+ x2*sc1 + sh1])
template <bool ADD2>
__global__ void k_fuse(const float* __restrict__ h, const float* __restrict__ x2,
                       const float* __restrict__ bnp, float* __restrict__ out) {
  int i = blockIdx.x * blockDim.x + threadIdx.x;
  int stride = gridDim.x * blockDim.x;
  const int n4 = N_NODES * D / 4;
  for (; i < n4; i += stride) {
    int c4 = (i & 63) * 4;
    float4 hv = ((const float4*)h)[i];
    float4 sc = *(const float4*)&bnp[c4];
    float4 sh = *(const float4*)&bnp[D + c4];
    float4 o;
    o.x = hv.x * sc.x + sh.x; o.y = hv.y * sc.y + sh.y;
    o.z = hv.z * sc.z + sh.z; o.w = hv.w * sc.w + sh.w;
    if (ADD2) {
      float4 pv = ((const float4*)x2)[i];
      float4 sc2 = *(const float4*)&bnp[2 * D + c4];
      float4 sh2 = *(const float4*)&bnp[3 * D + c4];
      o.x += pv.x * sc2.x + sh2.x; o.y += pv.y * sc2.y + sh2.y;
      o.z += pv.z * sc2.z + sh2.z; o.w += pv.w * sc2.w + sh2.w;
    }
    o.x = fmaxf(o.x, 0.f); o.y = fmaxf(o.y, 0.f);
    o.z = fmaxf(o.z, 0.f); o.w = fmaxf(o.w, 0.f);
    ((float4*)out)[i] = o;
  }
}

// concat [w_self_2; w_neigh_2] -> [80,256]
__global__ void k_wcat(const float* __restrict__ ws2, const float* __restrict__ wn2,
                       float* __restrict__ wcat) {
  int i = blockIdx.x * blockDim.x + threadIdx.x;
  if (i < 2 * NCLS * D) wcat[i] = (i < NCLS * D) ? ws2[i] : wn2[i - NCLS * D];
}

// out[n,j] = P[n,j] + b2[j] + agg40[n,j]*invdeg[n]
__global__ void k_final(const float* __restrict__ P, const float* __restrict__ agg40,
                        const float* __restrict__ invdeg, const float* __restrict__ b2,
                        float* __restrict__ out) {
  int i = blockIdx.x * blockDim.x + threadIdx.x;
  int stride = gridDim.x * blockDim.x;
  for (; i < N_NODES * NCLS; i += stride) {
    int n = i / NCLS, j = i - n * NCLS;
    out[i] = P[(size_t)n * 80 + j] + b2[j] + agg40[i] * invdeg[n];
  }
}

extern "C" void kernel_launch(void* const* d_in, const int* in_sizes, int n_in,
                              void* d_out, int out_size, void* d_ws, size_t ws_size,
                              hipStream_t stream) {
  const float* LLM = (const float*)d_in[0];
  const float* PLM = (const float*)d_in[1];
  const int* src = (const int*)d_in[2];
  const int* dst = (const int*)d_in[3];
  const float* ws0 = (const float*)d_in[4];
  const float* wn0 = (const float*)d_in[5];
  const float* b0  = (const float*)d_in[6];
  const float* ws1 = (const float*)d_in[7];
  const float* wn1 = (const float*)d_in[8];
  const float* b1  = (const float*)d_in[9];
  const float* ws2 = (const float*)d_in[10];
  const float* wn2 = (const float*)d_in[11];
  const float* b2  = (const float*)d_in[12];
  const float* bn0w = (const float*)d_in[13];
  const float* bn0b = (const float*)d_in[14];
  const float* bn1w = (const float*)d_in[15];
  const float* bn1b = (const float*)d_in[16];

  float* W = (float*)d_ws;
  float* f_invdeg = W;                         // 50048
  float* f_bnp    = W + 50048;                 // 1024
  float* f_stats  = W + 51072;                 // 1024
  float* f_wcat   = W + 52096;                 // 20480
  float* f_agg    = W + 72576;                 // 12.8M
  float* f_bufA   = W + 12872576;              // 12.8M
  float* f_bufB   = W + 25672576;              // 12.8M  (total ~154 MB)
  float* f_P      = f_bufA;                    // overlay: 50000*80
  float* f_agg40  = f_bufA + 4000000;          // overlay: 50000*40

  // ---- degree ----
  hipMemsetAsync(f_invdeg, 0, (size_t)N_NODES * 4, stream);
  hipMemsetAsync(f_stats, 0, 1024 * 4, stream);
  hipMemsetAsync(f_agg, 0, (size_t)N_NODES * D * 4, stream);
  k_deg<<<512, 256, 0, stream>>>(dst, f_invdeg);
  k_invdeg<<<(N_NODES + 255) / 256, 256, 0, stream>>>(f_invdeg);

  // ---- layer 0 ----
  k_scatter256<<<4096, 256, 0, stream>>>(LLM, src, dst, f_agg);
  k_gemm<true, true><<<dim3(391, 2), 256, 0, stream>>>(LLM, f_agg, f_invdeg, ws0, wn0, b0,
                                                       f_bufA, N_NODES, 256, 256);
  k_stats<<<512, 256, 0, stream>>>(f_bufA, f_stats);
  k_stats<<<512, 256, 0, stream>>>(PLM, f_stats + 512);
  k_bnparams<<<2, 256, 0, stream>>>(f_stats, bn0w, bn0b, f_bnp);
  k_fuse<true><<<2048, 256, 0, stream>>>(f_bufA, PLM, f_bnp, f_bufB);

  // ---- layer 1 ----
  hipMemsetAsync(f_stats, 0, 512 * 4, stream);
  hipMemsetAsync(f_agg, 0, (size_t)N_NODES * D * 4, stream);
  k_scatter256<<<4096, 256, 0, stream>>>(f_bufB, src, dst, f_agg);
  k_gemm<true, true><<<dim3(391, 2), 256, 0, stream>>>(f_bufB, f_agg, f_invdeg, ws1, wn1, b1,
                                                       f_bufA, N_NODES, 256, 256);
  k_stats<<<512, 256, 0, stream>>>(f_bufA, f_stats);
  k_bnparams<<<1, 256, 0, stream>>>(f_stats, bn1w, bn1b, f_bnp);
  k_fuse<false><<<2048, 256, 0, stream>>>(f_bufA, nullptr, f_bnp, f_bufB);

  // ---- layer 2: project-then-aggregate (40-dim scatter instead of 256) ----
  k_wcat<<<(2 * NCLS * D + 255) / 256, 256, 0, stream>>>(ws2, wn2, f_wcat);
  k_gemm<false, false><<<dim3(391, 1), 256, 0, stream>>>(f_bufB, nullptr, nullptr, f_wcat,
                                                         nullptr, nullptr, f_P, N_NODES, 80, 80);
  hipMemsetAsync(f_agg40, 0, (size_t)N_NODES * NCLS * 4, stream);
  k_scatter40<<<2048, 256, 0, stream>>>(f_P, src, dst, f_agg40);
  k_final<<<2048, 256, 0, stream>>>(f_P, f_agg40, f_invdeg, b2, (float*)d_out);
}

// Round 2
// 1228.532 us; speedup vs baseline: 5.1276x; 5.1276x over previous
//
#include <hip/hip_runtime.h>

#define N_NODES 50000
#define N_EDGES 800000
#define D 256
#define NCLS 40
#define NP 50176   // 196*256 padded histogram/scan size (>= N_NODES+1)
#define NB 196
#define BN_EPS 1e-5f

// ================= CSR build =================
__global__ void k_hist(const int* __restrict__ dst, int* __restrict__ cnt) {
  int i = blockIdx.x * blockDim.x + threadIdx.x;
  int stride = gridDim.x * blockDim.x;
  for (; i < N_EDGES; i += stride) atomicAdd(&cnt[dst[i] + 1], 1);
}

// inclusive scan of 256-chunk per block, record block totals
__global__ void k_scan1(int* __restrict__ a, int* __restrict__ bsum) {
  __shared__ int s[256];
  int i = blockIdx.x * 256 + threadIdx.x;
  s[threadIdx.x] = a[i];
  __syncthreads();
#pragma unroll
  for (int o = 1; o < 256; o <<= 1) {
    int t = (threadIdx.x >= o) ? s[threadIdx.x - o] : 0;
    __syncthreads();
    s[threadIdx.x] += t;
    __syncthreads();
  }
  a[i] = s[threadIdx.x];
  if (threadIdx.x == 255) bsum[blockIdx.x] = s[255];
}

// exclusive scan of NB block totals (single block)
__global__ void k_scan2(int* __restrict__ bsum) {
  __shared__ int s[256];
  int t = threadIdx.x;
  s[t] = (t < NB) ? bsum[t] : 0;
  __syncthreads();
#pragma unroll
  for (int o = 1; o < 256; o <<= 1) {
    int x = (t >= o) ? s[t - o] : 0;
    __syncthreads();
    s[t] += x;
    __syncthreads();
  }
  if (t < NB) bsum[t] = (t == 0) ? 0 : s[t - 1];
}

__global__ void k_scan3(int* __restrict__ a, const int* __restrict__ bsum) {
  if (blockIdx.x == 0) return;
  int i = blockIdx.x * 256 + threadIdx.x;
  a[i] += bsum[blockIdx.x];
}

__global__ void k_copycur(const int* __restrict__ off, int* __restrict__ cur) {
  int i = blockIdx.x * blockDim.x + threadIdx.x;
  if (i < N_NODES) cur[i] = off[i];
}

__global__ void k_fill(const int* __restrict__ src, const int* __restrict__ dst,
                       int* __restrict__ cur, int* __restrict__ esrc) {
  int i = blockIdx.x * blockDim.x + threadIdx.x;
  int stride = gridDim.x * blockDim.x;
  for (; i < N_EDGES; i += stride) {
    int p = atomicAdd(&cur[dst[i]], 1);
    esrc[p] = src[i];
  }
}

// ================= gather-mean (256 ch): one wave per node =================
__global__ __launch_bounds__(256) void k_gather256(const float* __restrict__ feat,
                                                   const int* __restrict__ off,
                                                   const int* __restrict__ esrc,
                                                   float* __restrict__ out) {
  int wave = blockIdx.x * 4 + (threadIdx.x >> 6);
  int lane = threadIdx.x & 63;
  if (wave >= N_NODES) return;
  int s0 = off[wave], s1 = off[wave + 1];
  float ax = 0.f, ay = 0.f, az = 0.f, aw = 0.f;
  int j = s0;
  for (; j + 1 < s1; j += 2) {
    int sa = esrc[j], sb = esrc[j + 1];
    float4 va = *(const float4*)&feat[(size_t)sa * D + lane * 4];
    float4 vb = *(const float4*)&feat[(size_t)sb * D + lane * 4];
    ax += va.x + vb.x; ay += va.y + vb.y;
    az += va.z + vb.z; aw += va.w + vb.w;
  }
  if (j < s1) {
    int sa = esrc[j];
    float4 va = *(const float4*)&feat[(size_t)sa * D + lane * 4];
    ax += va.x; ay += va.y; az += va.z; aw += va.w;
  }
  float inv = 1.0f / fmaxf((float)(s1 - s0), 1.0f);
  float4 o;
  o.x = ax * inv; o.y = ay * inv; o.z = az * inv; o.w = aw * inv;
  *(float4*)&out[(size_t)wave * D + lane * 4] = o;
}

// ================= gather-mean (40 ch) fused with final epilogue =================
// out[n,j] = P[n,j] + b2[j] + mean_neigh(P[s, 40+j])
__global__ __launch_bounds__(256) void k_gather40(const float* __restrict__ P,
                                                  const int* __restrict__ off,
                                                  const int* __restrict__ esrc,
                                                  const float* __restrict__ b2,
                                                  float* __restrict__ out) {
  int wave = blockIdx.x * 4 + (threadIdx.x >> 6);
  int lane = threadIdx.x & 63;
  if (wave >= N_NODES || lane >= NCLS) return;
  int s0 = off[wave], s1 = off[wave + 1];
  float acc = 0.f;
  for (int j = s0; j < s1; ++j) {
    int s = esrc[j];
    acc += P[(size_t)s * 80 + NCLS + lane];
  }
  float inv = 1.0f / fmaxf((float)(s1 - s0), 1.0f);
  out[(size_t)wave * NCLS + lane] = P[(size_t)wave * 80 + lane] + b2[lane] + acc * inv;
}

// ========== fused dual GEMM: Out = A1@W1^T + A2@W2^T (+bias); A2 pre-meaned ==========
template <bool DUAL, bool HASBIAS>
__global__ __launch_bounds__(256) void k_gemm(
    const float* __restrict__ A1, const float* __restrict__ A2,
    const float* __restrict__ W1, const float* __restrict__ W2,
    const float* __restrict__ bias,
    float* __restrict__ Out, int M, int ncolB, int ldc) {
  __shared__ float As1[16][132], Bs1[16][132], As2[16][132], Bs2[16][132];
  int tid = threadIdx.x;
  int m0 = blockIdx.x * 128, n0 = blockIdx.y * 128;
  int tx = tid & 15, ty = tid >> 4;
  float acc[8][8] = {};
  for (int k0 = 0; k0 < D; k0 += 16) {
#pragma unroll
    for (int p = 0; p < 2; ++p) {
      int idx = tid + p * 256;
      int r = idx >> 2;
      int kq = (idx & 3) << 2;
      int row = m0 + r; if (row > M - 1) row = M - 1;
      float4 a1 = *(const float4*)&A1[(size_t)row * D + k0 + kq];
      As1[kq + 0][r] = a1.x; As1[kq + 1][r] = a1.y;
      As1[kq + 2][r] = a1.z; As1[kq + 3][r] = a1.w;
      if (DUAL) {
        float4 a2 = *(const float4*)&A2[(size_t)row * D + k0 + kq];
        As2[kq + 0][r] = a2.x; As2[kq + 1][r] = a2.y;
        As2[kq + 2][r] = a2.z; As2[kq + 3][r] = a2.w;
      }
      int rb = n0 + r; if (rb > ncolB - 1) rb = ncolB - 1;
      float4 b1 = *(const float4*)&W1[(size_t)rb * D + k0 + kq];
      Bs1[kq + 0][r] = b1.x; Bs1[kq + 1][r] = b1.y;
      Bs1[kq + 2][r] = b1.z; Bs1[kq + 3][r] = b1.w;
      if (DUAL) {
        float4 b2 = *(const float4*)&W2[(size_t)rb * D + k0 + kq];
        Bs2[kq + 0][r] = b2.x; Bs2[kq + 1][r] = b2.y;
        Bs2[kq + 2][r] = b2.z; Bs2[kq + 3][r] = b2.w;
      }
    }
    __syncthreads();
#pragma unroll
    for (int kk = 0; kk < 16; ++kk) {
      float a1v[8], b1v[8];
      *(float4*)&a1v[0] = *(const float4*)&As1[kk][ty * 8];
      *(float4*)&a1v[4] = *(const float4*)&As1[kk][ty * 8 + 4];
      *(float4*)&b1v[0] = *(const float4*)&Bs1[kk][tx * 8];
      *(float4*)&b1v[4] = *(const float4*)&Bs1[kk][tx * 8 + 4];
#pragma unroll
      for (int i = 0; i < 8; ++i)
#pragma unroll
        for (int j = 0; j < 8; ++j) acc[i][j] += a1v[i] * b1v[j];
      if (DUAL) {
        float a2v[8], b2v[8];
        *(float4*)&a2v[0] = *(const float4*)&As2[kk][ty * 8];
        *(float4*)&a2v[4] = *(const float4*)&As2[kk][ty * 8 + 4];
        *(float4*)&b2v[0] = *(const float4*)&Bs2[kk][tx * 8];
        *(float4*)&b2v[4] = *(const float4*)&Bs2[kk][tx * 8 + 4];
#pragma unroll
        for (int i = 0; i < 8; ++i)
#pragma unroll
          for (int j = 0; j < 8; ++j) acc[i][j] += a2v[i] * b2v[j];
      }
    }
    __syncthreads();
  }
#pragma unroll
  for (int i = 0; i < 8; ++i) {
    int row = m0 + ty * 8 + i;
    if (row >= M) break;
#pragma unroll
    for (int j = 0; j < 8; j += 4) {
      int col = n0 + tx * 8 + j;
      if (col + 3 < ncolB) {
        float4 o;
        o.x = acc[i][j + 0]; o.y = acc[i][j + 1];
        o.z = acc[i][j + 2]; o.w = acc[i][j + 3];
        if (HASBIAS) {
          o.x += bias[col + 0]; o.y += bias[col + 1];
          o.z += bias[col + 2]; o.w += bias[col + 3];
        }
        *(float4*)&Out[(size_t)row * ldc + col] = o;
      } else {
        for (int q = 0; q < 4; ++q) {
          if (col + q < ncolB) {
            float v = acc[i][j + q];
            if (HASBIAS) v += bias[col + q];
            Out[(size_t)row * ldc + col + q] = v;
          }
        }
      }
    }
  }
}

// ================= batch-norm =================
__global__ void k_stats(const float* __restrict__ x, float* __restrict__ stats) {
  int c = threadIdx.x;
  float s = 0.f, ss = 0.f;
  for (int r = blockIdx.x; r < N_NODES; r += gridDim.x) {
    float v = x[(size_t)r * D + c];
    s += v; ss += v * v;
  }
  atomicAdd(&stats[c], s);
  atomicAdd(&stats[D + c], ss);
}

__global__ void k_bnparams(const float* __restrict__ stats, const float* __restrict__ w,
                           const float* __restrict__ b, float* __restrict__ bnp) {
  int set = blockIdx.x, c = threadIdx.x;
  const float* st = stats + (size_t)set * 2 * D;
  float m = st[c] * (1.0f / N_NODES);
  float var = st[D + c] * (1.0f / N_NODES) - m * m;
  float sc = rsqrtf(var + BN_EPS) * w[c];
  bnp[(size_t)set * 2 * D + c] = sc;
  bnp[(size_t)set * 2 * D + D + c] = b[c] - m * sc;
}

template <bool ADD2>
__global__ void k_fuse(const float* __restrict__ h, const float* __restrict__ x2,
                       const float* __restrict__ bnp, float* __restrict__ out) {
  int i = blockIdx.x * blockDim.x + threadIdx.x;
  int stride = gridDim.x * blockDim.x;
  const int n4 = N_NODES * D / 4;
  for (; i < n4; i += stride) {
    int c4 = (i & 63) * 4;
    float4 hv = ((const float4*)h)[i];
    float4 sc = *(const float4*)&bnp[c4];
    float4 sh = *(const float4*)&bnp[D + c4];
    float4 o;
    o.x = hv.x * sc.x + sh.x; o.y = hv.y * sc.y + sh.y;
    o.z = hv.z * sc.z + sh.z; o.w = hv.w * sc.w + sh.w;
    if (ADD2) {
      float4 pv = ((const float4*)x2)[i];
      float4 sc2 = *(const float4*)&bnp[2 * D + c4];
      float4 sh2 = *(const float4*)&bnp[3 * D + c4];
      o.x += pv.x * sc2.x + sh2.x; o.y += pv.y * sc2.y + sh2.y;
      o.z += pv.z * sc2.z + sh2.z; o.w += pv.w * sc2.w + sh2.w;
    }
    o.x = fmaxf(o.x, 0.f); o.y = fmaxf(o.y, 0.f);
    o.z = fmaxf(o.z, 0.f); o.w = fmaxf(o.w, 0.f);
    ((float4*)out)[i] = o;
  }
}

__global__ void k_wcat(const float* __restrict__ ws2, const float* __restrict__ wn2,
                       float* __restrict__ wcat) {
  int i = blockIdx.x * blockDim.x + threadIdx.x;
  if (i < 2 * NCLS * D) wcat[i] = (i < NCLS * D) ? ws2[i] : wn2[i - NCLS * D];
}

extern "C" void kernel_launch(void* const* d_in, const int* in_sizes, int n_in,
                              void* d_out, int out_size, void* d_ws, size_t ws_size,
                              hipStream_t stream) {
  const float* LLM = (const float*)d_in[0];
  const float* PLM = (const float*)d_in[1];
  const int* src = (const int*)d_in[2];
  const int* dst = (const int*)d_in[3];
  const float* ws0 = (const float*)d_in[4];
  const float* wn0 = (const float*)d_in[5];
  const float* b0  = (const float*)d_in[6];
  const float* ws1 = (const float*)d_in[7];
  const float* wn1 = (const float*)d_in[8];
  const float* b1  = (const float*)d_in[9];
  const float* ws2 = (const float*)d_in[10];
  const float* wn2 = (const float*)d_in[11];
  const float* b2  = (const float*)d_in[12];
  const float* bn0w = (const float*)d_in[13];
  const float* bn0b = (const float*)d_in[14];
  const float* bn1w = (const float*)d_in[15];
  const float* bn1b = (const float*)d_in[16];

  float* W = (float*)d_ws;
  float* f_bnp   = W;                 // 1024
  float* f_stats = W + 1024;          // 1024
  float* f_wcat  = W + 2048;          // 20480
  float* f_agg   = W + 22528;         // 12.8M
  float* f_bufA  = W + 12822528;      // 12.8M
  float* f_bufB  = W + 25622528;      // 12.8M   (total 153.7 MB)
  float* f_P     = f_agg;             // overlay: 50000*80 (free during layer 2)

  // CSR-A overlays bufB (untouched until layer-1 GEMM output)
  int* iA_off  = (int*)f_bufB;        // NP
  int* iA_bsum = iA_off + NP;         // 256
  int* iA_cur  = iA_bsum + 256;       // 50048
  int* iA_esrc = iA_cur + 50048;      // 800000
  // CSR-B overlays bufA (free after layer-1 GEMM reads it)
  int* iB_off  = (int*)f_bufA;
  int* iB_bsum = iB_off + NP;
  int* iB_cur  = iB_bsum + 256;
  int* iB_esrc = iB_cur + 50048;

  // ---- CSR build (phase A, in bufB) ----
  hipMemsetAsync(iA_off, 0, NP * sizeof(int), stream);
  k_hist<<<2048, 256, 0, stream>>>(dst, iA_off);
  k_scan1<<<NB, 256, 0, stream>>>(iA_off, iA_bsum);
  k_scan2<<<1, 256, 0, stream>>>(iA_bsum);
  k_scan3<<<NB, 256, 0, stream>>>(iA_off, iA_bsum);
  k_copycur<<<(N_NODES + 255) / 256, 256, 0, stream>>>(iA_off, iA_cur);
  k_fill<<<2048, 256, 0, stream>>>(src, dst, iA_cur, iA_esrc);

  // ---- layer 0 ----
  hipMemsetAsync(f_stats, 0, 1024 * sizeof(float), stream);
  k_gather256<<<12500, 256, 0, stream>>>(LLM, iA_off, iA_esrc, f_agg);
  k_gemm<true, true><<<dim3(391, 2), 256, 0, stream>>>(LLM, f_agg, ws0, wn0, b0,
                                                       f_bufA, N_NODES, 256, 256);
  k_stats<<<512, 256, 0, stream>>>(f_bufA, f_stats);
  k_stats<<<512, 256, 0, stream>>>(PLM, f_stats + 512);
  k_bnparams<<<2, 256, 0, stream>>>(f_stats, bn0w, bn0b, f_bnp);
  k_fuse<true><<<2048, 256, 0, stream>>>(f_bufA, PLM, f_bnp, f_bufA);  // in-place

  // ---- layer 1 ----
  hipMemsetAsync(f_stats, 0, 512 * sizeof(float), stream);
  k_gather256<<<12500, 256, 0, stream>>>(f_bufA, iA_off, iA_esrc, f_agg);
  k_gemm<true, true><<<dim3(391, 2), 256, 0, stream>>>(f_bufA, f_agg, ws1, wn1, b1,
                                                       f_bufB, N_NODES, 256, 256);  // destroys CSR-A
  k_stats<<<512, 256, 0, stream>>>(f_bufB, f_stats);
  k_bnparams<<<1, 256, 0, stream>>>(f_stats, bn1w, bn1b, f_bnp);
  k_fuse<false><<<2048, 256, 0, stream>>>(f_bufB, nullptr, f_bnp, f_bufB);  // in-place

  // ---- CSR rebuild (phase B, in bufA — free now) ----
  hipMemsetAsync(iB_off, 0, NP * sizeof(int), stream);
  k_hist<<<2048, 256, 0, stream>>>(dst, iB_off);
  k_scan1<<<NB, 256, 0, stream>>>(iB_off, iB_bsum);
  k_scan2<<<1, 256, 0, stream>>>(iB_bsum);
  k_scan3<<<NB, 256, 0, stream>>>(iB_off, iB_bsum);
  k_copycur<<<(N_NODES + 255) / 256, 256, 0, stream>>>(iB_off, iB_cur);
  k_fill<<<2048, 256, 0, stream>>>(src, dst, iB_cur, iB_esrc);

  // ---- layer 2: project (both halves) then gather-mean + epilogue ----
  k_wcat<<<(2 * NCLS * D + 255) / 256, 256, 0, stream>>>(ws2, wn2, f_wcat);
  k_gemm<false, false><<<dim3(391, 1), 256, 0, stream>>>(f_bufB, nullptr, f_wcat, nullptr,
                                                         nullptr, f_P, N_NODES, 80, 80);
  k_gather40<<<12500, 256, 0, stream>>>(f_P, iB_off, iB_esrc, b2, (float*)d_out);
}

// Round 5
// 934.204 us; speedup vs baseline: 6.7430x; 1.3151x over previous
//
#include <hip/hip_runtime.h>

#define N_NODES 50000
#define N_EDGES 800000
#define D 256
#define NCLS 40
#define NP 50176   // 196*256 padded histogram/scan size (>= N_NODES+1)
#define NB 196
#define BN_EPS 1e-5f

typedef __attribute__((ext_vector_type(8))) short bf16x8;
typedef __attribute__((ext_vector_type(4))) float f32x4;

__device__ __forceinline__ unsigned short f2bf(float x) {
  unsigned u = __builtin_bit_cast(unsigned, x);
  unsigned r = (u + 0x7FFFu + ((u >> 16) & 1u)) >> 16;
  return (unsigned short)r;
}
__device__ __forceinline__ float bf2f(unsigned short h) {
  unsigned u = ((unsigned)h) << 16;
  return __builtin_bit_cast(float, u);
}

// ================= CSR build =================
__global__ void k_hist(const int* __restrict__ dst, int* __restrict__ cnt) {
  int i = blockIdx.x * blockDim.x + threadIdx.x;
  int stride = gridDim.x * blockDim.x;
  for (; i < N_EDGES; i += stride) atomicAdd(&cnt[dst[i] + 1], 1);
}

__global__ void k_scan1(int* __restrict__ a, int* __restrict__ bsum) {
  __shared__ int s[256];
  int i = blockIdx.x * 256 + threadIdx.x;
  s[threadIdx.x] = a[i];
  __syncthreads();
#pragma unroll
  for (int o = 1; o < 256; o <<= 1) {
    int t = (threadIdx.x >= o) ? s[threadIdx.x - o] : 0;
    __syncthreads();
    s[threadIdx.x] += t;
    __syncthreads();
  }
  a[i] = s[threadIdx.x];
  if (threadIdx.x == 255) bsum[blockIdx.x] = s[255];
}

__global__ void k_scan2(int* __restrict__ bsum) {
  __shared__ int s[256];
  int t = threadIdx.x;
  s[t] = (t < NB) ? bsum[t] : 0;
  __syncthreads();
#pragma unroll
  for (int o = 1; o < 256; o <<= 1) {
    int x = (t >= o) ? s[t - o] : 0;
    __syncthreads();
    s[t] += x;
    __syncthreads();
  }
  if (t < NB) bsum[t] = (t == 0) ? 0 : s[t - 1];
}

__global__ void k_scan3(int* __restrict__ a, const int* __restrict__ bsum) {
  if (blockIdx.x == 0) return;
  int i = blockIdx.x * 256 + threadIdx.x;
  a[i] += bsum[blockIdx.x];
}

__global__ void k_copycur(const int* __restrict__ off, int* __restrict__ cur) {
  int i = blockIdx.x * blockDim.x + threadIdx.x;
  if (i < N_NODES) cur[i] = off[i];
}

__global__ void k_fill(const int* __restrict__ src, const int* __restrict__ dst,
                       int* __restrict__ cur, int* __restrict__ esrc) {
  int i = blockIdx.x * blockDim.x + threadIdx.x;
  int stride = gridDim.x * blockDim.x;
  for (; i < N_EDGES; i += stride) {
    int p = atomicAdd(&cur[dst[i]], 1);
    esrc[p] = src[i];
  }
}

// ================= gather-mean (256 ch): one wave per node =================
__global__ __launch_bounds__(256) void k_gather256(const float* __restrict__ feat,
                                                   const int* __restrict__ off,
                                                   const int* __restrict__ esrc,
                                                   float* __restrict__ out) {
  int wave = blockIdx.x * 4 + (threadIdx.x >> 6);
  int lane = threadIdx.x & 63;
  if (wave >= N_NODES) return;
  int s0 = off[wave], s1 = off[wave + 1];
  float ax = 0.f, ay = 0.f, az = 0.f, aw = 0.f;
  int j = s0;
  for (; j + 1 < s1; j += 2) {
    int sa = esrc[j], sb = esrc[j + 1];
    float4 va = *(const float4*)&feat[(size_t)sa * D + lane * 4];
    float4 vb = *(const float4*)&feat[(size_t)sb * D + lane * 4];
    ax += va.x + vb.x; ay += va.y + vb.y;
    az += va.z + vb.z; aw += va.w + vb.w;
  }
  if (j < s1) {
    int sa = esrc[j];
    float4 va = *(const float4*)&feat[(size_t)sa * D + lane * 4];
    ax += va.x; ay += va.y; az += va.z; aw += va.w;
  }
  float inv = 1.0f / fmaxf((float)(s1 - s0), 1.0f);
  float4 o;
  o.x = ax * inv; o.y = ay * inv; o.z = az * inv; o.w = aw * inv;
  *(float4*)&out[(size_t)wave * D + lane * 4] = o;
}

// ================= gather-mean (40 ch) fused with final epilogue =================
__global__ __launch_bounds__(256) void k_gather40(const float* __restrict__ P,
                                                  const int* __restrict__ off,
                                                  const int* __restrict__ esrc,
                                                  const float* __restrict__ b2,
                                                  float* __restrict__ out) {
  int wave = blockIdx.x * 4 + (threadIdx.x >> 6);
  int lane = threadIdx.x & 63;
  if (wave >= N_NODES || lane >= NCLS) return;
  int s0 = off[wave], s1 = off[wave + 1];
  float acc = 0.f;
  for (int j = s0; j < s1; ++j) {
    int s = esrc[j];
    acc += P[(size_t)s * 80 + NCLS + lane];
  }
  float inv = 1.0f / fmaxf((float)(s1 - s0), 1.0f);
  out[(size_t)wave * NCLS + lane] = P[(size_t)wave * 80 + lane] + b2[lane] + acc * inv;
}

// ========== split-bf16 MFMA GEMM ==========
// Out[M x ncol] = Acat @ Wcat^T (+bias), where Acat = [A1 | A2] (K = NSTEPS*64),
// Wcat rows = [W1; W2] rows, each stored [row][256] f32.
// fp32 emulated via bf16 hi/lo: a*w ~= ah*wh + ah*wl + al*wh (3 MFMA passes).
// 128x128 tile, BK=64, 4 waves (each 64x64), XOR-swizzled LDS (G4).
template <int NSTEPS, bool DUAL, bool HASBIAS>
__global__ __launch_bounds__(256) void k_mfma_gemm(
    const float* __restrict__ A1, const float* __restrict__ A2,
    const float* __restrict__ W1, const float* __restrict__ W2,
    const float* __restrict__ bias,
    float* __restrict__ Out, int M, int ncol, int ldc) {
  __shared__ short lsA_h[128 * 64], lsA_l[128 * 64];
  __shared__ short lsW_h[128 * 64], lsW_l[128 * 64];
  const int tid = threadIdx.x;
  const int lane = tid & 63;
  const int wv = tid >> 6;            // wave 0..3
  const int wr = wv >> 1, wc = wv & 1;
  const int m0 = blockIdx.x * 128, n0 = blockIdx.y * 128;

  f32x4 acc[4][4] = {};

  const int sr = tid >> 1;            // staging row 0..127
  const int sk = (tid & 1) * 32;      // f32 col offset 0/32

  int arow = m0 + sr; if (arow > M - 1) arow = M - 1;
  int wrow = n0 + sr; if (wrow > ncol - 1) wrow = ncol - 1;

  for (int s = 0; s < NSTEPS; ++s) {
    const float* Ap = (DUAL && s >= NSTEPS / 2) ? A2 : A1;
    const float* Wp = (DUAL && s >= NSTEPS / 2) ? W2 : W1;
    const int k0 = (DUAL ? (s & (NSTEPS / 2 - 1)) : s) * 64;
    const float* ap = &Ap[(size_t)arow * 256 + k0 + sk];
    const float* wp = &Wp[(size_t)wrow * 256 + k0 + sk];
    float av[32], wvv[32];
#pragma unroll
    for (int i = 0; i < 8; ++i) {
      *(float4*)&av[i * 4] = *(const float4*)&ap[i * 4];
      *(float4*)&wvv[i * 4] = *(const float4*)&wp[i * 4];
    }
    __syncthreads();  // previous iteration's LDS reads complete
#pragma unroll
    for (int c = 0; c < 4; ++c) {
      bf16x8 ah, al, wh, wl;
#pragma unroll
      for (int q = 0; q < 8; ++q) {
        float x = av[c * 8 + q];
        unsigned short h = f2bf(x);
        ah[q] = (short)h;
        al[q] = (short)f2bf(x - bf2f(h));
        float y = wvv[c * 8 + q];
        unsigned short hw = f2bf(y);
        wh[q] = (short)hw;
        wl[q] = (short)f2bf(y - bf2f(hw));
      }
      int byte = sk * 2 + c * 16;
      int idx = (sr * 128 + (byte ^ ((sr & 7) << 4))) >> 1;
      *(bf16x8*)&lsA_h[idx] = ah;
      *(bf16x8*)&lsA_l[idx] = al;
      *(bf16x8*)&lsW_h[idx] = wh;
      *(bf16x8*)&lsW_l[idx] = wl;
    }
    __syncthreads();
#pragma unroll
    for (int ks = 0; ks < 2; ++ks) {
      bf16x8 a_h[4], a_l[4], w_h[4], w_l[4];
      const int kb = ks * 64 + (lane >> 4) * 16;
#pragma unroll
      for (int i = 0; i < 4; ++i) {
        int rowA = wr * 64 + i * 16 + (lane & 15);
        int adA = (rowA * 128 + (kb ^ ((rowA & 7) << 4))) >> 1;
        a_h[i] = *(bf16x8*)&lsA_h[adA];
        a_l[i] = *(bf16x8*)&lsA_l[adA];
        int rowW = wc * 64 + i * 16 + (lane & 15);
        int adW = (rowW * 128 + (kb ^ ((rowW & 7) << 4))) >> 1;
        w_h[i] = *(bf16x8*)&lsW_h[adW];
        w_l[i] = *(bf16x8*)&lsW_l[adW];
      }
#pragma unroll
      for (int i = 0; i < 4; ++i)
#pragma unroll
        for (int j = 0; j < 4; ++j) {
          acc[i][j] = __builtin_amdgcn_mfma_f32_16x16x32_bf16(a_h[i], w_h[j], acc[i][j], 0, 0, 0);
          acc[i][j] = __builtin_amdgcn_mfma_f32_16x16x32_bf16(a_h[i], w_l[j], acc[i][j], 0, 0, 0);
          acc[i][j] = __builtin_amdgcn_mfma_f32_16x16x32_bf16(a_l[i], w_h[j], acc[i][j], 0, 0, 0);
        }
    }
  }
  // epilogue: C[row][col], col = lane&15 (+frag), row = (lane>>4)*4 + r (+frag)
#pragma unroll
  for (int j = 0; j < 4; ++j) {
    int col = n0 + wc * 64 + j * 16 + (lane & 15);
    if (col >= ncol) continue;
    float bv = HASBIAS ? bias[col] : 0.f;
#pragma unroll
    for (int i = 0; i < 4; ++i) {
#pragma unroll
      for (int r = 0; r < 4; ++r) {
        int row = m0 + wr * 64 + i * 16 + (lane >> 4) * 4 + r;
        if (row < M) Out[(size_t)row * ldc + col] = acc[i][j][r] + bv;
      }
    }
  }
}

// ================= batch-norm =================
__global__ void k_stats(const float* __restrict__ x, float* __restrict__ stats) {
  int c = threadIdx.x;
  float s = 0.f, ss = 0.f;
  for (int r = blockIdx.x; r < N_NODES; r += gridDim.x) {
    float v = x[(size_t)r * D + c];
    s += v; ss += v * v;
  }
  atomicAdd(&stats[c], s);
  atomicAdd(&stats[D + c], ss);
}

__global__ void k_bnparams(const float* __restrict__ stats, const float* __restrict__ w,
                           const float* __restrict__ b, float* __restrict__ bnp) {
  int set = blockIdx.x, c = threadIdx.x;
  const float* st = stats + (size_t)set * 2 * D;
  float m = st[c] * (1.0f / N_NODES);
  float var = st[D + c] * (1.0f / N_NODES) - m * m;
  float sc = rsqrtf(var + BN_EPS) * w[c];
  bnp[(size_t)set * 2 * D + c] = sc;
  bnp[(size_t)set * 2 * D + D + c] = b[c] - m * sc;
}

template <bool ADD2>
__global__ void k_fuse(const float* __restrict__ h, const float* __restrict__ x2,
                       const float* __restrict__ bnp, float* __restrict__ out) {
  int i = blockIdx.x * blockDim.x + threadIdx.x;
  int stride = gridDim.x * blockDim.x;
  const int n4 = N_NODES * D / 4;
  for (; i < n4; i += stride) {
    int c4 = (i & 63) * 4;
    float4 hv = ((const float4*)h)[i];
    float4 sc = *(const float4*)&bnp[c4];
    float4 sh = *(const float4*)&bnp[D + c4];
    float4 o;
    o.x = hv.x * sc.x + sh.x; o.y = hv.y * sc.y + sh.y;
    o.z = hv.z * sc.z + sh.z; o.w = hv.w * sc.w + sh.w;
    if (ADD2) {
      float4 pv = ((const float4*)x2)[i];
      float4 sc2 = *(const float4*)&bnp[2 * D + c4];
      float4 sh2 = *(const float4*)&bnp[3 * D + c4];
      o.x += pv.x * sc2.x + sh2.x; o.y += pv.y * sc2.y + sh2.y;
      o.z += pv.z * sc2.z + sh2.z; o.w += pv.w * sc2.w + sh2.w;
    }
    o.x = fmaxf(o.x, 0.f); o.y = fmaxf(o.y, 0.f);
    o.z = fmaxf(o.z, 0.f); o.w = fmaxf(o.w, 0.f);
    ((float4*)out)[i] = o;
  }
}

__global__ void k_wcat(const float* __restrict__ ws2, const float* __restrict__ wn2,
                       float* __restrict__ wcat) {
  int i = blockIdx.x * blockDim.x + threadIdx.x;
  if (i < 2 * NCLS * D) wcat[i] = (i < NCLS * D) ? ws2[i] : wn2[i - NCLS * D];
}

extern "C" void kernel_launch(void* const* d_in, const int* in_sizes, int n_in,
                              void* d_out, int out_size, void* d_ws, size_t ws_size,
                              hipStream_t stream) {
  const float* LLM = (const float*)d_in[0];
  const float* PLM = (const float*)d_in[1];
  const int* src = (const int*)d_in[2];
  const int* dst = (const int*)d_in[3];
  const float* ws0 = (const float*)d_in[4];
  const float* wn0 = (const float*)d_in[5];
  const float* b0  = (const float*)d_in[6];
  const float* ws1 = (const float*)d_in[7];
  const float* wn1 = (const float*)d_in[8];
  const float* b1  = (const float*)d_in[9];
  const float* ws2 = (const float*)d_in[10];
  const float* wn2 = (const float*)d_in[11];
  const float* b2  = (const float*)d_in[12];
  const float* bn0w = (const float*)d_in[13];
  const float* bn0b = (const float*)d_in[14];
  const float* bn1w = (const float*)d_in[15];
  const float* bn1b = (const float*)d_in[16];

  float* W = (float*)d_ws;
  float* f_bnp   = W;                 // 1024
  float* f_stats = W + 1024;          // 1024
  float* f_wcat  = W + 2048;          // 20480
  float* f_agg   = W + 22528;         // 12.8M
  float* f_bufA  = W + 12822528;      // 12.8M
  float* f_bufB  = W + 25622528;      // 12.8M
  float* f_P     = f_agg;             // overlay (agg free during layer 2)

  // Dedicated CSR region (path A) needs 157.3 MB total
  const size_t NEED_A = (size_t)(38422528 + NP + 256 + 50048 + N_EDGES) * 4;
  const bool bigws = ws_size >= NEED_A;

  int* iD_off  = (int*)(W + 38422528);
  int* iD_bsum = iD_off + NP;
  int* iD_cur  = iD_bsum + 256;
  int* iD_esrc = iD_cur + 50048;

  // Path-B overlays (CSR-A in bufB, CSR-B rebuilt in bufA)
  int* iA_off  = bigws ? iD_off  : (int*)f_bufB;
  int* iA_bsum = bigws ? iD_bsum : iA_off + NP;
  int* iA_cur  = bigws ? iD_cur  : iA_bsum + 256;
  int* iA_esrc = bigws ? iD_esrc : iA_cur + 50048;
  int* iB_off  = (int*)f_bufA;
  int* iB_bsum = iB_off + NP;
  int* iB_cur  = iB_bsum + 256;
  int* iB_esrc = iB_cur + 50048;

  // ---- CSR build ----
  hipMemsetAsync(iA_off, 0, NP * sizeof(int), stream);
  k_hist<<<2048, 256, 0, stream>>>(dst, iA_off);
  k_scan1<<<NB, 256, 0, stream>>>(iA_off, iA_bsum);
  k_scan2<<<1, 256, 0, stream>>>(iA_bsum);
  k_scan3<<<NB, 256, 0, stream>>>(iA_off, iA_bsum);
  k_copycur<<<(N_NODES + 255) / 256, 256, 0, stream>>>(iA_off, iA_cur);
  k_fill<<<2048, 256, 0, stream>>>(src, dst, iA_cur, iA_esrc);

  // ---- layer 0 ----
  hipMemsetAsync(f_stats, 0, 1024 * sizeof(float), stream);
  k_gather256<<<12500, 256, 0, stream>>>(LLM, iA_off, iA_esrc, f_agg);
  k_mfma_gemm<8, true, true><<<dim3(391, 2), 256, 0, stream>>>(
      LLM, f_agg, ws0, wn0, b0, f_bufA, N_NODES, 256, 256);
  k_stats<<<512, 256, 0, stream>>>(f_bufA, f_stats);
  k_stats<<<512, 256, 0, stream>>>(PLM, f_stats + 512);
  k_bnparams<<<2, 256, 0, stream>>>(f_stats, bn0w, bn0b, f_bnp);
  k_fuse<true><<<2048, 256, 0, stream>>>(f_bufA, PLM, f_bnp, f_bufA);  // in-place

  // ---- layer 1 ----
  hipMemsetAsync(f_stats, 0, 512 * sizeof(float), stream);
  k_gather256<<<12500, 256, 0, stream>>>(f_bufA, iA_off, iA_esrc, f_agg);
  k_mfma_gemm<8, true, true><<<dim3(391, 2), 256, 0, stream>>>(
      f_bufA, f_agg, ws1, wn1, b1, f_bufB, N_NODES, 256, 256);  // destroys CSR-A iff !bigws
  k_stats<<<512, 256, 0, stream>>>(f_bufB, f_stats);
  k_bnparams<<<1, 256, 0, stream>>>(f_stats, bn1w, bn1b, f_bnp);
  k_fuse<false><<<2048, 256, 0, stream>>>(f_bufB, nullptr, f_bnp, f_bufB);  // in-place

  // ---- CSR rebuild only if no dedicated region ----
  int* g_off = iA_off; int* g_esrc = iA_esrc;
  if (!bigws) {
    hipMemsetAsync(iB_off, 0, NP * sizeof(int), stream);
    k_hist<<<2048, 256, 0, stream>>>(dst, iB_off);
    k_scan1<<<NB, 256, 0, stream>>>(iB_off, iB_bsum);
    k_scan2<<<1, 256, 0, stream>>>(iB_bsum);
    k_scan3<<<NB, 256, 0, stream>>>(iB_off, iB_bsum);
    k_copycur<<<(N_NODES + 255) / 256, 256, 0, stream>>>(iB_off, iB_cur);
    k_fill<<<2048, 256, 0, stream>>>(src, dst, iB_cur, iB_esrc);
    g_off = iB_off; g_esrc = iB_esrc;
  }

  // ---- layer 2: project (both halves) then gather-mean + epilogue ----
  k_wcat<<<(2 * NCLS * D + 255) / 256, 256, 0, stream>>>(ws2, wn2, f_wcat);
  k_mfma_gemm<4, false, false><<<dim3(391, 1), 256, 0, stream>>>(
      f_bufB, nullptr, f_wcat, nullptr, nullptr, f_P, N_NODES, 80, 80);
  k_gather40<<<12500, 256, 0, stream>>>(f_P, g_off, g_esrc, b2, (float*)d_out);
}

// Round 6
// 782.886 us; speedup vs baseline: 8.0463x; 1.1933x over previous
//
#include <hip/hip_runtime.h>

#define N_NODES 50000
#define N_EDGES 800000
#define D 256
#define NCLS 40
#define NP 50176   // 196*256 padded histogram/scan size (>= N_NODES+1)
#define NB 196
#define BN_EPS 1e-5f

typedef __attribute__((ext_vector_type(8))) short bf16x8;
typedef __attribute__((ext_vector_type(4))) float f32x4;

__device__ __forceinline__ unsigned short f2bf(float x) {
  unsigned u = __builtin_bit_cast(unsigned, x);
  unsigned r = (u + 0x7FFFu + ((u >> 16) & 1u)) >> 16;
  return (unsigned short)r;
}
__device__ __forceinline__ float bf2f(unsigned short h) {
  unsigned u = ((unsigned)h) << 16;
  return __builtin_bit_cast(float, u);
}

// ================= CSR build =================
__global__ void k_hist(const int* __restrict__ dst, int* __restrict__ cnt) {
  int i = blockIdx.x * blockDim.x + threadIdx.x;
  int stride = gridDim.x * blockDim.x;
  for (; i < N_EDGES; i += stride) atomicAdd(&cnt[dst[i] + 1], 1);
}

__global__ void k_scan1(int* __restrict__ a, int* __restrict__ bsum) {
  __shared__ int s[256];
  int i = blockIdx.x * 256 + threadIdx.x;
  s[threadIdx.x] = a[i];
  __syncthreads();
#pragma unroll
  for (int o = 1; o < 256; o <<= 1) {
    int t = (threadIdx.x >= o) ? s[threadIdx.x - o] : 0;
    __syncthreads();
    s[threadIdx.x] += t;
    __syncthreads();
  }
  a[i] = s[threadIdx.x];
  if (threadIdx.x == 255) bsum[blockIdx.x] = s[255];
}

__global__ void k_scan2(int* __restrict__ bsum) {
  __shared__ int s[256];
  int t = threadIdx.x;
  s[t] = (t < NB) ? bsum[t] : 0;
  __syncthreads();
#pragma unroll
  for (int o = 1; o < 256; o <<= 1) {
    int x = (t >= o) ? s[t - o] : 0;
    __syncthreads();
    s[t] += x;
    __syncthreads();
  }
  if (t < NB) bsum[t] = (t == 0) ? 0 : s[t - 1];
}

__global__ void k_scan3(int* __restrict__ a, const int* __restrict__ bsum) {
  if (blockIdx.x == 0) return;
  int i = blockIdx.x * 256 + threadIdx.x;
  a[i] += bsum[blockIdx.x];
}

__global__ void k_copycur(const int* __restrict__ off, int* __restrict__ cur) {
  int i = blockIdx.x * blockDim.x + threadIdx.x;
  if (i < N_NODES) cur[i] = off[i];
}

__global__ void k_fill(const int* __restrict__ src, const int* __restrict__ dst,
                       int* __restrict__ cur, int* __restrict__ esrc) {
  int i = blockIdx.x * blockDim.x + threadIdx.x;
  int stride = gridDim.x * blockDim.x;
  for (; i < N_EDGES; i += stride) {
    int p = atomicAdd(&cur[dst[i]], 1);
    esrc[p] = src[i];
  }
}

// ====== gather-mean over bf16 table (stride-512 rows), output bf16 ======
// feat = hi-plane h-half base; aggout = hi-plane agg-half base (col offset pre-applied)
__global__ __launch_bounds__(256) void k_gather_bf(const unsigned short* __restrict__ feat,
                                                   const int* __restrict__ off,
                                                   const int* __restrict__ esrc,
                                                   unsigned short* __restrict__ aggout) {
  int wave = blockIdx.x * 4 + (threadIdx.x >> 6);
  int lane = threadIdx.x & 63;
  if (wave >= N_NODES) return;
  int s0 = off[wave], s1 = off[wave + 1];
  float a0 = 0.f, a1 = 0.f, a2 = 0.f, a3 = 0.f;
  int j = s0;
  for (; j + 1 < s1; j += 2) {
    int sa = esrc[j], sb = esrc[j + 1];
    ushort4 va = *(const ushort4*)&feat[(size_t)sa * 512 + lane * 4];
    ushort4 vb = *(const ushort4*)&feat[(size_t)sb * 512 + lane * 4];
    a0 += bf2f(va.x) + bf2f(vb.x);
    a1 += bf2f(va.y) + bf2f(vb.y);
    a2 += bf2f(va.z) + bf2f(vb.z);
    a3 += bf2f(va.w) + bf2f(vb.w);
  }
  if (j < s1) {
    int sa = esrc[j];
    ushort4 va = *(const ushort4*)&feat[(size_t)sa * 512 + lane * 4];
    a0 += bf2f(va.x); a1 += bf2f(va.y); a2 += bf2f(va.z); a3 += bf2f(va.w);
  }
  float inv = 1.0f / fmaxf((float)(s1 - s0), 1.0f);
  ushort4 o;
  o.x = f2bf(a0 * inv); o.y = f2bf(a1 * inv);
  o.z = f2bf(a2 * inv); o.w = f2bf(a3 * inv);
  *(ushort4*)&aggout[(size_t)wave * 512 + lane * 4] = o;
}

// ====== gather-mean (40 ch, f32 P) fused with final epilogue ======
__global__ __launch_bounds__(256) void k_gather40(const float* __restrict__ P,
                                                  const int* __restrict__ off,
                                                  const int* __restrict__ esrc,
                                                  const float* __restrict__ b2,
                                                  float* __restrict__ out) {
  int wave = blockIdx.x * 4 + (threadIdx.x >> 6);
  int lane = threadIdx.x & 63;
  if (wave >= N_NODES || lane >= NCLS) return;
  int s0 = off[wave], s1 = off[wave + 1];
  float acc = 0.f;
  for (int j = s0; j < s1; ++j) {
    int s = esrc[j];
    acc += P[(size_t)s * 80 + NCLS + lane];
  }
  float inv = 1.0f / fmaxf((float)(s1 - s0), 1.0f);
  out[(size_t)wave * NCLS + lane] = P[(size_t)wave * 80 + lane] + b2[lane] + acc * inv;
}

// ====== f32 -> hi/lo bf16 planes (layer-0 LLM features) ======
__global__ void k_cvt(const float* __restrict__ x, unsigned short* __restrict__ hi,
                      unsigned short* __restrict__ lo) {
  int i = blockIdx.x * blockDim.x + threadIdx.x;
  int stride = gridDim.x * blockDim.x;
  const int n4 = N_NODES * D / 4;
  for (; i < n4; i += stride) {
    int row = i >> 6;
    int c4 = (i & 63) * 4;
    float4 v = ((const float4*)x)[i];
    ushort4 h, l;
    h.x = f2bf(v.x); l.x = f2bf(v.x - bf2f(h.x));
    h.y = f2bf(v.y); l.y = f2bf(v.y - bf2f(h.y));
    h.z = f2bf(v.z); l.z = f2bf(v.z - bf2f(h.z));
    h.w = f2bf(v.w); l.w = f2bf(v.w - bf2f(h.w));
    *(ushort4*)&hi[(size_t)row * 512 + c4] = h;
    *(ushort4*)&lo[(size_t)row * 256 + c4] = l;
  }
}

// ====== weight split: Wcat [256][512] hi/lo from W1,W2 [256][256] ======
__global__ void k_wsplit512(const float* __restrict__ W1, const float* __restrict__ W2,
                            unsigned short* __restrict__ Wh, unsigned short* __restrict__ Wl) {
  int i = blockIdx.x * blockDim.x + threadIdx.x;  // 256*128 threads, 4 elems each
  if (i >= 256 * 128) return;
  int row = i >> 7;
  int c4 = (i & 127) * 4;
  const float* srcp = (c4 < 256) ? &W1[(size_t)row * 256 + c4] : &W2[(size_t)row * 256 + c4 - 256];
  float4 v = *(const float4*)srcp;
  ushort4 h, l;
  h.x = f2bf(v.x); l.x = f2bf(v.x - bf2f(h.x));
  h.y = f2bf(v.y); l.y = f2bf(v.y - bf2f(h.y));
  h.z = f2bf(v.z); l.z = f2bf(v.z - bf2f(h.z));
  h.w = f2bf(v.w); l.w = f2bf(v.w - bf2f(h.w));
  *(ushort4*)&Wh[(size_t)row * 512 + c4] = h;
  *(ushort4*)&Wl[(size_t)row * 512 + c4] = l;
}

// ====== weight split layer 2: Wcat2 [80][256] hi/lo from ws2,wn2 [40][256] ======
__global__ void k_wsplit2(const float* __restrict__ ws2, const float* __restrict__ wn2,
                          unsigned short* __restrict__ Wh, unsigned short* __restrict__ Wl) {
  int i = blockIdx.x * blockDim.x + threadIdx.x;  // 80*64 threads, 4 elems each
  if (i >= 80 * 64) return;
  int row = i >> 6;
  int c4 = (i & 63) * 4;
  const float* srcp = (row < NCLS) ? &ws2[(size_t)row * 256 + c4]
                                   : &wn2[(size_t)(row - NCLS) * 256 + c4];
  float4 v = *(const float4*)srcp;
  ushort4 h, l;
  h.x = f2bf(v.x); l.x = f2bf(v.x - bf2f(h.x));
  h.y = f2bf(v.y); l.y = f2bf(v.y - bf2f(h.y));
  h.z = f2bf(v.z); l.z = f2bf(v.z - bf2f(h.z));
  h.w = f2bf(v.w); l.w = f2bf(v.w - bf2f(h.w));
  *(ushort4*)&Wh[(size_t)row * 256 + c4] = h;
  *(ushort4*)&Wl[(size_t)row * 256 + c4] = l;
}

// ========== bf16 MFMA GEMM over pre-split planes ==========
// Out[M x ncol] = A @ W^T (+bias). A: hi plane (stride strideA) + lo plane (stride 256,
// only K-steps s < NLO). W: hi/lo planes (stride strideW). 3 passes (ah*wh+ah*wl+al*wh)
// for s<NLO, 2 passes otherwise. 128x128 tile, BK=64, 4 waves, XOR-swizzled LDS.
template <int NSTEPS, int NLO, bool HASBIAS>
__global__ __launch_bounds__(256) void k_bgemm(
    const unsigned short* __restrict__ Ah, int strideA,
    const unsigned short* __restrict__ Al,
    const unsigned short* __restrict__ Wh, const unsigned short* __restrict__ Wl, int strideW,
    const float* __restrict__ bias,
    float* __restrict__ Out, int M, int ncol, int ldc) {
  __shared__ short sAh[128 * 64], sAl[128 * 64], sWh[128 * 64], sWl[128 * 64];
  const int tid = threadIdx.x;
  const int lane = tid & 63;
  const int wv = tid >> 6;
  const int wr = wv >> 1, wc = wv & 1;
  const int m0 = blockIdx.x * 128, n0 = blockIdx.y * 128;

  f32x4 acc[4][4] = {};

  const int sr = tid >> 1;            // staging row 0..127
  const int sk2 = (tid & 1) * 32;     // bf16 col offset 0/32

  int arow = m0 + sr; if (arow > M - 1) arow = M - 1;
  int wrow = n0 + sr; if (wrow > ncol - 1) wrow = ncol - 1;

#pragma unroll
  for (int s = 0; s < NSTEPS; ++s) {
    const bool withLo = (s < NLO);
    const int k0 = s * 64;
    const unsigned short* pa  = Ah + (size_t)arow * strideA + k0 + sk2;
    const unsigned short* pal = Al + (size_t)arow * 256 + k0 + sk2;
    const unsigned short* pw  = Wh + (size_t)wrow * strideW + k0 + sk2;
    const unsigned short* pwl = Wl + (size_t)wrow * strideW + k0 + sk2;
    bf16x8 ra[4], ral[4], rw[4], rwl[4];
#pragma unroll
    for (int c = 0; c < 4; ++c) {
      ra[c]  = *(const bf16x8*)(pa + c * 8);
      rw[c]  = *(const bf16x8*)(pw + c * 8);
      rwl[c] = *(const bf16x8*)(pwl + c * 8);
      if (withLo) ral[c] = *(const bf16x8*)(pal + c * 8);
    }
    __syncthreads();  // previous iteration's LDS reads complete
#pragma unroll
    for (int c = 0; c < 4; ++c) {
      int byte = (sk2 + c * 8) * 2;
      int idx = (sr * 128 + (byte ^ ((sr & 7) << 4))) >> 1;
      *(bf16x8*)&sAh[idx] = ra[c];
      *(bf16x8*)&sWh[idx] = rw[c];
      *(bf16x8*)&sWl[idx] = rwl[c];
      if (withLo) *(bf16x8*)&sAl[idx] = ral[c];
    }
    __syncthreads();
#pragma unroll
    for (int ks = 0; ks < 2; ++ks) {
      bf16x8 a_h[4], a_l[4], w_h[4], w_l[4];
      const int kb = ks * 64 + (lane >> 4) * 16;
#pragma unroll
      for (int i = 0; i < 4; ++i) {
        int rowA = wr * 64 + i * 16 + (lane & 15);
        int adA = (rowA * 128 + (kb ^ ((rowA & 7) << 4))) >> 1;
        a_h[i] = *(bf16x8*)&sAh[adA];
        if (withLo) a_l[i] = *(bf16x8*)&sAl[adA];
        int rowW = wc * 64 + i * 16 + (lane & 15);
        int adW = (rowW * 128 + (kb ^ ((rowW & 7) << 4))) >> 1;
        w_h[i] = *(bf16x8*)&sWh[adW];
        w_l[i] = *(bf16x8*)&sWl[adW];
      }
#pragma unroll
      for (int i = 0; i < 4; ++i)
#pragma unroll
        for (int j = 0; j < 4; ++j) {
          acc[i][j] = __builtin_amdgcn_mfma_f32_16x16x32_bf16(a_h[i], w_h[j], acc[i][j], 0, 0, 0);
          acc[i][j] = __builtin_amdgcn_mfma_f32_16x16x32_bf16(a_h[i], w_l[j], acc[i][j], 0, 0, 0);
          if (withLo)
            acc[i][j] = __builtin_amdgcn_mfma_f32_16x16x32_bf16(a_l[i], w_h[j], acc[i][j], 0, 0, 0);
        }
    }
  }
  // epilogue: C[row][col], col = lane&15 (+frag), row = (lane>>4)*4 + r (+frag)
#pragma unroll
  for (int j = 0; j < 4; ++j) {
    int col = n0 + wc * 64 + j * 16 + (lane & 15);
    if (col >= ncol) continue;
    float bv = HASBIAS ? bias[col] : 0.f;
#pragma unroll
    for (int i = 0; i < 4; ++i) {
#pragma unroll
      for (int r = 0; r < 4; ++r) {
        int row = m0 + wr * 64 + i * 16 + (lane >> 4) * 4 + r;
        if (row < M) Out[(size_t)row * ldc + col] = acc[i][j][r] + bv;
      }
    }
  }
}

// ================= batch-norm =================
__global__ void k_stats(const float* __restrict__ x, float* __restrict__ stats) {
  int c = threadIdx.x;
  float s = 0.f, ss = 0.f;
  for (int r = blockIdx.x; r < N_NODES; r += gridDim.x) {
    float v = x[(size_t)r * D + c];
    s += v; ss += v * v;
  }
  atomicAdd(&stats[c], s);
  atomicAdd(&stats[D + c], ss);
}

__global__ void k_bnparams(const float* __restrict__ stats, const float* __restrict__ w,
                           const float* __restrict__ b, float* __restrict__ bnp) {
  int set = blockIdx.x, c = threadIdx.x;
  const float* st = stats + (size_t)set * 2 * D;
  float m = st[c] * (1.0f / N_NODES);
  float var = st[D + c] * (1.0f / N_NODES) - m * m;
  float sc = rsqrtf(var + BN_EPS) * w[c];
  bnp[(size_t)set * 2 * D + c] = sc;
  bnp[(size_t)set * 2 * D + D + c] = b[c] - m * sc;
}

// out = relu(h*sc0 + sh0 [+ x2*sc1 + sh1]) -> hi/lo bf16 planes
template <bool ADD2>
__global__ void k_fusebf(const float* __restrict__ h, const float* __restrict__ x2,
                         const float* __restrict__ bnp,
                         unsigned short* __restrict__ hi, unsigned short* __restrict__ lo) {
  int i = blockIdx.x * blockDim.x + threadIdx.x;
  int stride = gridDim.x * blockDim.x;
  const int n4 = N_NODES * D / 4;
  for (; i < n4; i += stride) {
    int row = i >> 6;
    int c4 = (i & 63) * 4;
    float4 hv = ((const float4*)h)[i];
    float4 sc = *(const float4*)&bnp[c4];
    float4 sh = *(const float4*)&bnp[D + c4];
    float4 o;
    o.x = hv.x * sc.x + sh.x; o.y = hv.y * sc.y + sh.y;
    o.z = hv.z * sc.z + sh.z; o.w = hv.w * sc.w + sh.w;
    if (ADD2) {
      float4 pv = ((const float4*)x2)[i];
      float4 sc2 = *(const float4*)&bnp[2 * D + c4];
      float4 sh2 = *(const float4*)&bnp[3 * D + c4];
      o.x += pv.x * sc2.x + sh2.x; o.y += pv.y * sc2.y + sh2.y;
      o.z += pv.z * sc2.z + sh2.z; o.w += pv.w * sc2.w + sh2.w;
    }
    o.x = fmaxf(o.x, 0.f); o.y = fmaxf(o.y, 0.f);
    o.z = fmaxf(o.z, 0.f); o.w = fmaxf(o.w, 0.f);
    ushort4 H, L;
    H.x = f2bf(o.x); L.x = f2bf(o.x - bf2f(H.x));
    H.y = f2bf(o.y); L.y = f2bf(o.y - bf2f(H.y));
    H.z = f2bf(o.z); L.z = f2bf(o.z - bf2f(H.z));
    H.w = f2bf(o.w); L.w = f2bf(o.w - bf2f(H.w));
    *(ushort4*)&hi[(size_t)row * 512 + c4] = H;
    *(ushort4*)&lo[(size_t)row * 256 + c4] = L;
  }
}

extern "C" void kernel_launch(void* const* d_in, const int* in_sizes, int n_in,
                              void* d_out, int out_size, void* d_ws, size_t ws_size,
                              hipStream_t stream) {
  const float* LLM = (const float*)d_in[0];
  const float* PLM = (const float*)d_in[1];
  const int* src = (const int*)d_in[2];
  const int* dst = (const int*)d_in[3];
  const float* ws0 = (const float*)d_in[4];
  const float* wn0 = (const float*)d_in[5];
  const float* b0  = (const float*)d_in[6];
  const float* ws1 = (const float*)d_in[7];
  const float* wn1 = (const float*)d_in[8];
  const float* b1  = (const float*)d_in[9];
  const float* ws2 = (const float*)d_in[10];
  const float* wn2 = (const float*)d_in[11];
  const float* b2  = (const float*)d_in[12];
  const float* bn0w = (const float*)d_in[13];
  const float* bn0b = (const float*)d_in[14];
  const float* bn1w = (const float*)d_in[15];
  const float* bn1b = (const float*)d_in[16];

  float* W = (float*)d_ws;
  // ---- memory map (float offsets), total ~33.4M floats = 133.6 MB ----
  float* f_out = W;                               // [50000][256] f32 (51.2 MB)
  float* f_P   = W + 8000000;                     //   overlay: [50000][80] f32 (layer 2)
  unsigned short* u_hi = (unsigned short*)(W + 12800000);  // [50000][512] bf16 (51.2 MB)
  unsigned short* u_lo = (unsigned short*)(W + 25600000);  // [50000][256] bf16 (25.6 MB)
  int* i_off  = (int*)(W + 32000000);             // NP
  int* i_bsum = i_off + NP;                       // 256
  int* i_cur  = i_bsum + 256;                     // 50048
  int* i_esrc = i_cur + 50048;                    // 800000  (CSR total ~3.6 MB)
  unsigned short* u_w0h = (unsigned short*)(W + 33000000);   // [256][512]
  unsigned short* u_w0l = u_w0h + 131072;
  unsigned short* u_w1h = u_w0l + 131072;
  unsigned short* u_w1l = u_w1h + 131072;
  unsigned short* u_w2h = u_w1l + 131072;         // [80][256]
  unsigned short* u_w2l = u_w2h + 20480;
  float* f_stats = (float*)(u_w2l + 20480);       // 1024
  float* f_bnp   = f_stats + 1024;                // 1024

  // ---- CSR build (once, dedicated region) ----
  hipMemsetAsync(i_off, 0, NP * sizeof(int), stream);
  hipMemsetAsync(f_stats, 0, 1024 * sizeof(float), stream);
  k_hist<<<2048, 256, 0, stream>>>(dst, i_off);
  k_scan1<<<NB, 256, 0, stream>>>(i_off, i_bsum);
  k_scan2<<<1, 256, 0, stream>>>(i_bsum);
  k_scan3<<<NB, 256, 0, stream>>>(i_off, i_bsum);
  k_copycur<<<(N_NODES + 255) / 256, 256, 0, stream>>>(i_off, i_cur);
  k_fill<<<2048, 256, 0, stream>>>(src, dst, i_cur, i_esrc);

  // ---- weight splits ----
  k_wsplit512<<<128, 256, 0, stream>>>(ws0, wn0, u_w0h, u_w0l);
  k_wsplit512<<<128, 256, 0, stream>>>(ws1, wn1, u_w1h, u_w1l);
  k_wsplit2<<<20, 256, 0, stream>>>(ws2, wn2, u_w2h, u_w2l);

  // ---- layer 0 ----
  k_cvt<<<2048, 256, 0, stream>>>(LLM, u_hi, u_lo);
  k_gather_bf<<<12500, 256, 0, stream>>>(u_hi, i_off, i_esrc, u_hi + 256);
  k_bgemm<8, 4, true><<<dim3(391, 2), 256, 0, stream>>>(
      u_hi, 512, u_lo, u_w0h, u_w0l, 512, b0, f_out, N_NODES, 256, 256);
  k_stats<<<512, 256, 0, stream>>>(f_out, f_stats);
  k_stats<<<512, 256, 0, stream>>>(PLM, f_stats + 512);
  k_bnparams<<<2, 256, 0, stream>>>(f_stats, bn0w, bn0b, f_bnp);
  k_fusebf<true><<<2048, 256, 0, stream>>>(f_out, PLM, f_bnp, u_hi, u_lo);

  // ---- layer 1 ----
  hipMemsetAsync(f_stats, 0, 512 * sizeof(float), stream);
  k_gather_bf<<<12500, 256, 0, stream>>>(u_hi, i_off, i_esrc, u_hi + 256);
  k_bgemm<8, 4, true><<<dim3(391, 2), 256, 0, stream>>>(
      u_hi, 512, u_lo, u_w1h, u_w1l, 512, b1, f_out, N_NODES, 256, 256);
  k_stats<<<512, 256, 0, stream>>>(f_out, f_stats);
  k_bnparams<<<1, 256, 0, stream>>>(f_stats, bn1w, bn1b, f_bnp);
  k_fusebf<false><<<2048, 256, 0, stream>>>(f_out, nullptr, f_bnp, u_hi, u_lo);

  // ---- layer 2: project (K=256, h planes only) then gather-mean + epilogue ----
  k_bgemm<4, 4, false><<<dim3(391, 1), 256, 0, stream>>>(
      u_hi, 512, u_lo, u_w2h, u_w2l, 256, nullptr, f_P, N_NODES, 80, 80);
  k_gather40<<<12500, 256, 0, stream>>>(f_P, i_off, i_esrc, b2, (float*)d_out);
}

// Round 8
// 723.556 us; speedup vs baseline: 8.7061x; 1.0820x over previous
//
#include <hip/hip_runtime.h>

#define N_NODES 50000
#define N_EDGES 800000
#define D 256
#define NCLS 40
#define NP 50176   // 196*256 padded histogram/scan size (>= N_NODES+1)
#define NB 196
#define BN_EPS 1e-5f

typedef __attribute__((ext_vector_type(8))) short bf16x8;
typedef __attribute__((ext_vector_type(4))) float f32x4;

__device__ __forceinline__ unsigned short f2bf(float x) {
  unsigned u = __builtin_bit_cast(unsigned, x);
  unsigned r = (u + 0x7FFFu + ((u >> 16) & 1u)) >> 16;
  return (unsigned short)r;
}
__device__ __forceinline__ float bf2f(unsigned short h) {
  unsigned u = ((unsigned)h) << 16;
  return __builtin_bit_cast(float, u);
}

// ================= CSR build =================
__global__ void k_hist(const int* __restrict__ dst, int* __restrict__ cnt) {
  int i = blockIdx.x * blockDim.x + threadIdx.x;
  int stride = gridDim.x * blockDim.x;
  for (; i < N_EDGES; i += stride) atomicAdd(&cnt[dst[i] + 1], 1);
}

__global__ void k_scan1(int* __restrict__ a, int* __restrict__ bsum) {
  __shared__ int s[256];
  int i = blockIdx.x * 256 + threadIdx.x;
  s[threadIdx.x] = a[i];
  __syncthreads();
#pragma unroll
  for (int o = 1; o < 256; o <<= 1) {
    int t = (threadIdx.x >= o) ? s[threadIdx.x - o] : 0;
    __syncthreads();
    s[threadIdx.x] += t;
    __syncthreads();
  }
  a[i] = s[threadIdx.x];
  if (threadIdx.x == 255) bsum[blockIdx.x] = s[255];
}

__global__ void k_scan2(int* __restrict__ bsum) {
  __shared__ int s[256];
  int t = threadIdx.x;
  s[t] = (t < NB) ? bsum[t] : 0;
  __syncthreads();
#pragma unroll
  for (int o = 1; o < 256; o <<= 1) {
    int x = (t >= o) ? s[t - o] : 0;
    __syncthreads();
    s[t] += x;
    __syncthreads();
  }
  if (t < NB) bsum[t] = (t == 0) ? 0 : s[t - 1];
}

__global__ void k_scan3(int* __restrict__ a, const int* __restrict__ bsum) {
  if (blockIdx.x == 0) return;
  int i = blockIdx.x * 256 + threadIdx.x;
  a[i] += bsum[blockIdx.x];
}

__global__ void k_copycur(const int* __restrict__ off, int* __restrict__ cur) {
  int i = blockIdx.x * blockDim.x + threadIdx.x;
  if (i < N_NODES) cur[i] = off[i];
}

__global__ void k_fill(const int* __restrict__ src, const int* __restrict__ dst,
                       int* __restrict__ cur, int* __restrict__ esrc) {
  int i = blockIdx.x * blockDim.x + threadIdx.x;
  int stride = gridDim.x * blockDim.x;
  for (; i < N_EDGES; i += stride) {
    int p = atomicAdd(&cur[dst[i]], 1);
    esrc[p] = src[i];
  }
}

// ====== gather-mean over bf16 table (stride-512 rows), output bf16 ======
// unroll-4: 4 independent row loads in flight to hide L2/L3/HBM latency
__global__ __launch_bounds__(256) void k_gather_bf(const unsigned short* __restrict__ feat,
                                                   const int* __restrict__ off,
                                                   const int* __restrict__ esrc,
                                                   unsigned short* __restrict__ aggout) {
  int wave = blockIdx.x * 4 + (threadIdx.x >> 6);
  int lane = threadIdx.x & 63;
  if (wave >= N_NODES) return;
  int s0 = off[wave], s1 = off[wave + 1];
  float a0 = 0.f, a1 = 0.f, a2 = 0.f, a3 = 0.f;
  int j = s0;
  for (; j + 3 < s1; j += 4) {
    int sa = esrc[j], sb = esrc[j + 1], sc = esrc[j + 2], sd = esrc[j + 3];
    ushort4 va = *(const ushort4*)&feat[(size_t)sa * 512 + lane * 4];
    ushort4 vb = *(const ushort4*)&feat[(size_t)sb * 512 + lane * 4];
    ushort4 vc = *(const ushort4*)&feat[(size_t)sc * 512 + lane * 4];
    ushort4 vd = *(const ushort4*)&feat[(size_t)sd * 512 + lane * 4];
    a0 += (bf2f(va.x) + bf2f(vb.x)) + (bf2f(vc.x) + bf2f(vd.x));
    a1 += (bf2f(va.y) + bf2f(vb.y)) + (bf2f(vc.y) + bf2f(vd.y));
    a2 += (bf2f(va.z) + bf2f(vb.z)) + (bf2f(vc.z) + bf2f(vd.z));
    a3 += (bf2f(va.w) + bf2f(vb.w)) + (bf2f(vc.w) + bf2f(vd.w));
  }
  for (; j < s1; ++j) {
    int sa = esrc[j];
    ushort4 va = *(const ushort4*)&feat[(size_t)sa * 512 + lane * 4];
    a0 += bf2f(va.x); a1 += bf2f(va.y); a2 += bf2f(va.z); a3 += bf2f(va.w);
  }
  float inv = 1.0f / fmaxf((float)(s1 - s0), 1.0f);
  ushort4 o;
  o.x = f2bf(a0 * inv); o.y = f2bf(a1 * inv);
  o.z = f2bf(a2 * inv); o.w = f2bf(a3 * inv);
  *(ushort4*)&aggout[(size_t)wave * 512 + lane * 4] = o;
}

// ====== gather-mean (40 ch, f32 P) fused with final epilogue; unroll-4 ======
__global__ __launch_bounds__(256) void k_gather40(const float* __restrict__ P,
                                                  const int* __restrict__ off,
                                                  const int* __restrict__ esrc,
                                                  const float* __restrict__ b2,
                                                  float* __restrict__ out) {
  int wave = blockIdx.x * 4 + (threadIdx.x >> 6);
  int lane = threadIdx.x & 63;
  if (wave >= N_NODES || lane >= NCLS) return;
  int s0 = off[wave], s1 = off[wave + 1];
  float acc = 0.f;
  int j = s0;
  for (; j + 3 < s1; j += 4) {
    int sa = esrc[j], sb = esrc[j + 1], sc = esrc[j + 2], sd = esrc[j + 3];
    float va = P[(size_t)sa * 80 + NCLS + lane];
    float vb = P[(size_t)sb * 80 + NCLS + lane];
    float vc = P[(size_t)sc * 80 + NCLS + lane];
    float vd = P[(size_t)sd * 80 + NCLS + lane];
    acc += (va + vb) + (vc + vd);
  }
  for (; j < s1; ++j) {
    int s = esrc[j];
    acc += P[(size_t)s * 80 + NCLS + lane];
  }
  float inv = 1.0f / fmaxf((float)(s1 - s0), 1.0f);
  out[(size_t)wave * NCLS + lane] = P[(size_t)wave * 80 + lane] + b2[lane] + acc * inv;
}

// ====== f32 -> hi/lo bf16 planes (layer-0 LLM features) ======
__global__ void k_cvt(const float* __restrict__ x, unsigned short* __restrict__ hi,
                      unsigned short* __restrict__ lo) {
  int i = blockIdx.x * blockDim.x + threadIdx.x;
  int stride = gridDim.x * blockDim.x;
  const int n4 = N_NODES * D / 4;
  for (; i < n4; i += stride) {
    int row = i >> 6;
    int c4 = (i & 63) * 4;
    float4 v = ((const float4*)x)[i];
    ushort4 h, l;
    h.x = f2bf(v.x); l.x = f2bf(v.x - bf2f(h.x));
    h.y = f2bf(v.y); l.y = f2bf(v.y - bf2f(h.y));
    h.z = f2bf(v.z); l.z = f2bf(v.z - bf2f(h.z));
    h.w = f2bf(v.w); l.w = f2bf(v.w - bf2f(h.w));
    *(ushort4*)&hi[(size_t)row * 512 + c4] = h;
    *(ushort4*)&lo[(size_t)row * 256 + c4] = l;
  }
}

// ====== weight split: Wcat [256][512] hi/lo from W1,W2 [256][256] ======
__global__ void k_wsplit512(const float* __restrict__ W1, const float* __restrict__ W2,
                            unsigned short* __restrict__ Wh, unsigned short* __restrict__ Wl) {
  int i = blockIdx.x * blockDim.x + threadIdx.x;  // 256*128 threads, 4 elems each
  if (i >= 256 * 128) return;
  int row = i >> 7;
  int c4 = (i & 127) * 4;
  const float* srcp = (c4 < 256) ? &W1[(size_t)row * 256 + c4] : &W2[(size_t)row * 256 + c4 - 256];
  float4 v = *(const float4*)srcp;
  ushort4 h, l;
  h.x = f2bf(v.x); l.x = f2bf(v.x - bf2f(h.x));
  h.y = f2bf(v.y); l.y = f2bf(v.y - bf2f(h.y));
  h.z = f2bf(v.z); l.z = f2bf(v.z - bf2f(h.z));
  h.w = f2bf(v.w); l.w = f2bf(v.w - bf2f(h.w));
  *(ushort4*)&Wh[(size_t)row * 512 + c4] = h;
  *(ushort4*)&Wl[(size_t)row * 512 + c4] = l;
}

// ====== weight split layer 2: Wcat2 [80][256] hi/lo from ws2,wn2 [40][256] ======
__global__ void k_wsplit2(const float* __restrict__ ws2, const float* __restrict__ wn2,
                          unsigned short* __restrict__ Wh, unsigned short* __restrict__ Wl) {
  int i = blockIdx.x * blockDim.x + threadIdx.x;  // 80*64 threads, 4 elems each
  if (i >= 80 * 64) return;
  int row = i >> 6;
  int c4 = (i & 63) * 4;
  const float* srcp = (row < NCLS) ? &ws2[(size_t)row * 256 + c4]
                                   : &wn2[(size_t)(row - NCLS) * 256 + c4];
  float4 v = *(const float4*)srcp;
  ushort4 h, l;
  h.x = f2bf(v.x); l.x = f2bf(v.x - bf2f(h.x));
  h.y = f2bf(v.y); l.y = f2bf(v.y - bf2f(h.y));
  h.z = f2bf(v.z); l.z = f2bf(v.z - bf2f(h.z));
  h.w = f2bf(v.w); l.w = f2bf(v.w - bf2f(h.w));
  *(ushort4*)&Wh[(size_t)row * 256 + c4] = h;
  *(ushort4*)&Wl[(size_t)row * 256 + c4] = l;
}

// ========== bf16 MFMA GEMM over pre-split planes ==========
// Out[M x ncol] = A @ W^T (+bias). A: hi plane (stride strideA) + lo plane (stride 256,
// only K-steps s < NLO). W: hi/lo planes (stride strideW). 3 passes (ah*wh+ah*wl+al*wh)
// for s<NLO, 2 passes otherwise. 128x128 tile, BK=64, 4 waves, XOR-swizzled LDS.
template <int NSTEPS, int NLO, bool HASBIAS>
__global__ __launch_bounds__(256) void k_bgemm(
    const unsigned short* __restrict__ Ah, int strideA,
    const unsigned short* __restrict__ Al,
    const unsigned short* __restrict__ Wh, const unsigned short* __restrict__ Wl, int strideW,
    const float* __restrict__ bias,
    float* __restrict__ Out, int M, int ncol, int ldc) {
  __shared__ short sAh[128 * 64], sAl[128 * 64], sWh[128 * 64], sWl[128 * 64];
  const int tid = threadIdx.x;
  const int lane = tid & 63;
  const int wv = tid >> 6;
  const int wr = wv >> 1, wc = wv & 1;
  const int m0 = blockIdx.x * 128, n0 = blockIdx.y * 128;

  f32x4 acc[4][4] = {};

  const int sr = tid >> 1;            // staging row 0..127
  const int sk2 = (tid & 1) * 32;     // bf16 col offset 0/32

  int arow = m0 + sr; if (arow > M - 1) arow = M - 1;
  int wrow = n0 + sr; if (wrow > ncol - 1) wrow = ncol - 1;

#pragma unroll
  for (int s = 0; s < NSTEPS; ++s) {
    const bool withLo = (s < NLO);
    const int k0 = s * 64;
    const unsigned short* pa  = Ah + (size_t)arow * strideA + k0 + sk2;
    const unsigned short* pal = Al + (size_t)arow * 256 + k0 + sk2;
    const unsigned short* pw  = Wh + (size_t)wrow * strideW + k0 + sk2;
    const unsigned short* pwl = Wl + (size_t)wrow * strideW + k0 + sk2;
    bf16x8 ra[4], ral[4], rw[4], rwl[4];
#pragma unroll
    for (int c = 0; c < 4; ++c) {
      ra[c]  = *(const bf16x8*)(pa + c * 8);
      rw[c]  = *(const bf16x8*)(pw + c * 8);
      rwl[c] = *(const bf16x8*)(pwl + c * 8);
      if (withLo) ral[c] = *(const bf16x8*)(pal + c * 8);
    }
    __syncthreads();  // previous iteration's LDS reads complete
#pragma unroll
    for (int c = 0; c < 4; ++c) {
      int byte = (sk2 + c * 8) * 2;
      int idx = (sr * 128 + (byte ^ ((sr & 7) << 4))) >> 1;
      *(bf16x8*)&sAh[idx] = ra[c];
      *(bf16x8*)&sWh[idx] = rw[c];
      *(bf16x8*)&sWl[idx] = rwl[c];
      if (withLo) *(bf16x8*)&sAl[idx] = ral[c];
    }
    __syncthreads();
#pragma unroll
    for (int ks = 0; ks < 2; ++ks) {
      bf16x8 a_h[4], a_l[4], w_h[4], w_l[4];
      const int kb = ks * 64 + (lane >> 4) * 16;
#pragma unroll
      for (int i = 0; i < 4; ++i) {
        int rowA = wr * 64 + i * 16 + (lane & 15);
        int adA = (rowA * 128 + (kb ^ ((rowA & 7) << 4))) >> 1;
        a_h[i] = *(bf16x8*)&sAh[adA];
        if (withLo) a_l[i] = *(bf16x8*)&sAl[adA];
        int rowW = wc * 64 + i * 16 + (lane & 15);
        int adW = (rowW * 128 + (kb ^ ((rowW & 7) << 4))) >> 1;
        w_h[i] = *(bf16x8*)&sWh[adW];
        w_l[i] = *(bf16x8*)&sWl[adW];
      }
#pragma unroll
      for (int i = 0; i < 4; ++i)
#pragma unroll
        for (int j = 0; j < 4; ++j) {
          acc[i][j] = __builtin_amdgcn_mfma_f32_16x16x32_bf16(a_h[i], w_h[j], acc[i][j], 0, 0, 0);
          acc[i][j] = __builtin_amdgcn_mfma_f32_16x16x32_bf16(a_h[i], w_l[j], acc[i][j], 0, 0, 0);
          if (withLo)
            acc[i][j] = __builtin_amdgcn_mfma_f32_16x16x32_bf16(a_l[i], w_h[j], acc[i][j], 0, 0, 0);
        }
    }
  }
  // epilogue: C[row][col], col = lane&15 (+frag), row = (lane>>4)*4 + r (+frag)
#pragma unroll
  for (int j = 0; j < 4; ++j) {
    int col = n0 + wc * 64 + j * 16 + (lane & 15);
    if (col >= ncol) continue;
    float bv = HASBIAS ? bias[col] : 0.f;
#pragma unroll
    for (int i = 0; i < 4; ++i) {
#pragma unroll
      for (int r = 0; r < 4; ++r) {
        int row = m0 + wr * 64 + i * 16 + (lane >> 4) * 4 + r;
        if (row < M) Out[(size_t)row * ldc + col] = acc[i][j][r] + bv;
      }
    }
  }
}

// ================= batch-norm =================
__global__ void k_stats(const float* __restrict__ x, float* __restrict__ stats) {
  int c = threadIdx.x;
  float s = 0.f, ss = 0.f;
  for (int r = blockIdx.x; r < N_NODES; r += gridDim.x) {
    float v = x[(size_t)r * D + c];
    s += v; ss += v * v;
  }
  atomicAdd(&stats[c], s);
  atomicAdd(&stats[D + c], ss);
}

__global__ void k_bnparams(const float* __restrict__ stats, const float* __restrict__ w,
                           const float* __restrict__ b, float* __restrict__ bnp) {
  int set = blockIdx.x, c = threadIdx.x;
  const float* st = stats + (size_t)set * 2 * D;
  float m = st[c] * (1.0f / N_NODES);
  float var = st[D + c] * (1.0f / N_NODES) - m * m;
  float sc = rsqrtf(var + BN_EPS) * w[c];
  bnp[(size_t)set * 2 * D + c] = sc;
  bnp[(size_t)set * 2 * D + D + c] = b[c] - m * sc;
}

// out = relu(h*sc0 + sh0 [+ x2*sc1 + sh1]) -> hi/lo bf16 planes
template <bool ADD2>
__global__ void k_fusebf(const float* __restrict__ h, const float* __restrict__ x2,
                         const float* __restrict__ bnp,
                         unsigned short* __restrict__ hi, unsigned short* __restrict__ lo) {
  int i = blockIdx.x * blockDim.x + threadIdx.x;
  int stride = gridDim.x * blockDim.x;
  const int n4 = N_NODES * D / 4;
  for (; i < n4; i += stride) {
    int row = i >> 6;
    int c4 = (i & 63) * 4;
    float4 hv = ((const float4*)h)[i];
    float4 sc = *(const float4*)&bnp[c4];
    float4 sh = *(const float4*)&bnp[D + c4];
    float4 o;
    o.x = hv.x * sc.x + sh.x; o.y = hv.y * sc.y + sh.y;
    o.z = hv.z * sc.z + sh.z; o.w = hv.w * sc.w + sh.w;
    if (ADD2) {
      float4 pv = ((const float4*)x2)[i];
      float4 sc2 = *(const float4*)&bnp[2 * D + c4];
      float4 sh2 = *(const float4*)&bnp[3 * D + c4];
      o.x += pv.x * sc2.x + sh2.x; o.y += pv.y * sc2.y + sh2.y;
      o.z += pv.z * sc2.z + sh2.z; o.w += pv.w * sc2.w + sh2.w;
    }
    o.x = fmaxf(o.x, 0.f); o.y = fmaxf(o.y, 0.f);
    o.z = fmaxf(o.z, 0.f); o.w = fmaxf(o.w, 0.f);
    ushort4 H, L;
    H.x = f2bf(o.x); L.x = f2bf(o.x - bf2f(H.x));
    H.y = f2bf(o.y); L.y = f2bf(o.y - bf2f(H.y));
    H.z = f2bf(o.z); L.z = f2bf(o.z - bf2f(H.z));
    H.w = f2bf(o.w); L.w = f2bf(o.w - bf2f(H.w));
    *(ushort4*)&hi[(size_t)row * 512 + c4] = H;
    *(ushort4*)&lo[(size_t)row * 256 + c4] = L;
  }
}

extern "C" void kernel_launch(void* const* d_in, const int* in_sizes, int n_in,
                              void* d_out, int out_size, void* d_ws, size_t ws_size,
                              hipStream_t stream) {
  const float* LLM = (const float*)d_in[0];
  const float* PLM = (const float*)d_in[1];
  const int* src = (const int*)d_in[2];
  const int* dst = (const int*)d_in[3];
  const float* ws0 = (const float*)d_in[4];
  const float* wn0 = (const float*)d_in[5];
  const float* b0  = (const float*)d_in[6];
  const float* ws1 = (const float*)d_in[7];
  const float* wn1 = (const float*)d_in[8];
  const float* b1  = (const float*)d_in[9];
  const float* ws2 = (const float*)d_in[10];
  const float* wn2 = (const float*)d_in[11];
  const float* b2  = (const float*)d_in[12];
  const float* bn0w = (const float*)d_in[13];
  const float* bn0b = (const float*)d_in[14];
  const float* bn1w = (const float*)d_in[15];
  const float* bn1b = (const float*)d_in[16];

  float* W = (float*)d_ws;
  // ---- memory map (float offsets), total ~33.4M floats = 133.6 MB ----
  float* f_out = W;                               // [50000][256] f32 (51.2 MB)
  float* f_P   = W + 8000000;                     //   overlay: [50000][80] f32 (layer 2)
  unsigned short* u_hi = (unsigned short*)(W + 12800000);  // [50000][512] bf16 (51.2 MB)
  unsigned short* u_lo = (unsigned short*)(W + 25600000);  // [50000][256] bf16 (25.6 MB)
  int* i_off  = (int*)(W + 32000000);             // NP
  int* i_bsum = i_off + NP;                       // 256
  int* i_cur  = i_bsum + 256;                     // 50048
  int* i_esrc = i_cur + 50048;                    // 800000  (CSR total ~3.6 MB)
  unsigned short* u_w0h = (unsigned short*)(W + 33000000);   // [256][512]
  unsigned short* u_w0l = u_w0h + 131072;
  unsigned short* u_w1h = u_w0l + 131072;
  unsigned short* u_w1l = u_w1h + 131072;
  unsigned short* u_w2h = u_w1l + 131072;         // [80][256]
  unsigned short* u_w2l = u_w2h + 20480;
  float* f_stats = (float*)(u_w2l + 20480);       // 1024
  float* f_bnp   = f_stats + 1024;                // 1024

  // ---- CSR build (once, dedicated region) ----
  hipMemsetAsync(i_off, 0, NP * sizeof(int), stream);
  hipMemsetAsync(f_stats, 0, 1024 * sizeof(float), stream);
  k_hist<<<2048, 256, 0, stream>>>(dst, i_off);
  k_scan1<<<NB, 256, 0, stream>>>(i_off, i_bsum);
  k_scan2<<<1, 256, 0, stream>>>(i_bsum);
  k_scan3<<<NB, 256, 0, stream>>>(i_off, i_bsum);
  k_copycur<<<(N_NODES + 255) / 256, 256, 0, stream>>>(i_off, i_cur);
  k_fill<<<2048, 256, 0, stream>>>(src, dst, i_cur, i_esrc);

  // ---- weight splits ----
  k_wsplit512<<<128, 256, 0, stream>>>(ws0, wn0, u_w0h, u_w0l);
  k_wsplit512<<<128, 256, 0, stream>>>(ws1, wn1, u_w1h, u_w1l);
  k_wsplit2<<<20, 256, 0, stream>>>(ws2, wn2, u_w2h, u_w2l);

  // ---- layer 0 ----
  k_cvt<<<2048, 256, 0, stream>>>(LLM, u_hi, u_lo);
  k_gather_bf<<<12500, 256, 0, stream>>>(u_hi, i_off, i_esrc, u_hi + 256);
  k_bgemm<8, 4, true><<<dim3(391, 2), 256, 0, stream>>>(
      u_hi, 512, u_lo, u_w0h, u_w0l, 512, b0, f_out, N_NODES, 256, 256);
  k_stats<<<512, 256, 0, stream>>>(f_out, f_stats);
  k_stats<<<512, 256, 0, stream>>>(PLM, f_stats + 512);
  k_bnparams<<<2, 256, 0, stream>>>(f_stats, bn0w, bn0b, f_bnp);
  k_fusebf<true><<<2048, 256, 0, stream>>>(f_out, PLM, f_bnp, u_hi, u_lo);

  // ---- layer 1 ----
  hipMemsetAsync(f_stats, 0, 512 * sizeof(float), stream);
  k_gather_bf<<<12500, 256, 0, stream>>>(u_hi, i_off, i_esrc, u_hi + 256);
  k_bgemm<8, 4, true><<<dim3(391, 2), 256, 0, stream>>>(
      u_hi, 512, u_lo, u_w1h, u_w1l, 512, b1, f_out, N_NODES, 256, 256);
  k_stats<<<512, 256, 0, stream>>>(f_out, f_stats);
  k_bnparams<<<1, 256, 0, stream>>>(f_stats, bn1w, bn1b, f_bnp);
  k_fusebf<false><<<2048, 256, 0, stream>>>(f_out, nullptr, f_bnp, u_hi, u_lo);

  // ---- layer 2: project (K=256, h planes only) then gather-mean + epilogue ----
  k_bgemm<4, 4, false><<<dim3(391, 1), 256, 0, stream>>>(
      u_hi, 512, u_lo, u_w2h, u_w2l, 256, nullptr, f_P, N_NODES, 80, 80);
  k_gather40<<<12500, 256, 0, stream>>>(f_P, i_off, i_esrc, b2, (float*)d_out);
}